// Round 16
// baseline (236.360 us; speedup 1.0000x reference)
//
#include <hip/hip_runtime.h>
#include <hip/hip_bf16.h>

typedef __attribute__((ext_vector_type(8))) short short8;
typedef __attribute__((ext_vector_type(4))) short short4v;
typedef __attribute__((ext_vector_type(4))) float f32x4;
typedef __attribute__((ext_vector_type(4))) int int4v;
typedef unsigned long long u64;

#define HH 128
#define WW 128
#define CC 128
#define COUT 128
#define HO 64
#define WO 64
#define KK 9
#define PXB 64
#define NREC (KK * PXB)   /* 576 */

__device__ __forceinline__ unsigned short bf16bits(float f) {
    union { float f; unsigned u; } u; u.f = f;
    unsigned r = u.u + 0x7fffu + ((u.u >> 16) & 1u);
    return (unsigned short)(r >> 16);
}
__device__ __forceinline__ float b2f(unsigned short h) {
    union { unsigned u; float f; } v; v.u = ((unsigned)h) << 16; return v.f;
}

// Fused prep: blocks [0,1024): x NCHW f32 -> xt NHWC bf16 (one block per (b,y));
//             blocks [1024,1600): weight [Cout][C][9] f32 -> wp [9][Cout][C] bf16;
//             block 1600: zero the 512 pair-counters.
__global__ __launch_bounds__(256, 4)
void prep_kernel(const float* __restrict__ x, unsigned short* __restrict__ xt,
                 const float* __restrict__ w, unsigned short* __restrict__ wp,
                 int* __restrict__ cnt) {
    const int blk = blockIdx.x;
    const int t = threadIdx.x;
    __shared__ unsigned short tile[128][132];

    if (blk < 1024) {
        const int b = blk >> 7;
        const int y = blk & 127;
        const float* src = x + (((size_t)b * CC) * HH + y) * WW;
#pragma unroll 8
        for (int c0 = 0; c0 < CC; c0 += 2) {
            int c = c0 + (t >> 7);
            int xx = t & 127;
            tile[xx][c] = bf16bits(src[(size_t)c * (HH * WW) + xx]);
        }
        __syncthreads();
        unsigned short* dst = xt + (((size_t)b * HH + y) * WW) * CC;
#pragma unroll
        for (int it = 0; it < 4; ++it) {
            int lin = it * 256 + t;
            int xx = lin >> 3;
            int cb = (lin & 7) * 16;
            const u64* lp = (const u64*)&tile[xx][cb];
            u64* op = (u64*)(dst + (size_t)xx * CC + cb);
            op[0] = lp[0]; op[1] = lp[1]; op[2] = lp[2]; op[3] = lp[3];
        }
    } else if (blk < 1600) {
        int i = (blk - 1024) * 256 + t;
        if (i < KK * COUT * CC) {
            int kp = i / (COUT * CC);
            int r = i - kp * (COUT * CC);
            int o = r >> 7;
            int c = r & 127;
            wp[i] = bf16bits(w[((size_t)o * CC + c) * KK + kp]);
        }
    } else {
        cnt[t] = 0;
        cnt[t + 256] = 0;
    }
}

// Main kernel: R14 window internals VERBATIM. SPLIT epilogue = split-K
// semaphore merge: chalf0 writes raw partial to out (final addresses, no
// bias); chalf1 writes coalesced f32x4 partial to part1; threadfence +
// per-pair counter atomicAdd; the LAST finisher reads partner's partial,
// computes (partner + own) + bias (commutative -> deterministic bits),
// writes final out. No atomics on data, no extra launch.
template <bool SPLIT>
__global__ __launch_bounds__(256, 4)
void dcn16_kernel(const unsigned short* __restrict__ xt, const float* __restrict__ offset,
                  const float* __restrict__ mask, const unsigned short* __restrict__ wprep,
                  const float* __restrict__ bias, float* __restrict__ out,
                  float* __restrict__ part1, int* __restrict__ cnt) {
    const int blk = blockIdx.x;
    const int b = blk & 7;               // XCD i streams batch image i
    const int ho = (blk >> 3) & 63;
    const int chalf = SPLIT ? (blk >> 9) : 0;
    const int t = threadIdx.x;
    const int lane = t & 63;
    const int wid = t >> 6;

    __shared__ int            s_cidx[NREC][4];   // corner offsets, pre-scaled by CC
    __shared__ float          s_w[NREC][4];      // bilinear weights * mask (0 if OOB)
    __shared__ unsigned short s_val[PXB][72];    // bf16 val tile [px 64][c64 pad72]
    __shared__ int            s_last;

    // ---- per-(kp,wo) sampling records (same math as R1/R5/R7/R9/R14) ----
    for (int e = t; e < NREC; e += 256) {
        int kp = e >> 6;
        int wo = e & 63;
        int ky = kp / 3, kx = kp - ky * 3;
        float dy = offset[(((size_t)b * 18 + 2 * kp    ) * HO + ho) * WO + wo];
        float dx = offset[(((size_t)b * 18 + 2 * kp + 1) * HO + ho) * WO + wo];
        float m  = mask  [(((size_t)b * 9  + kp        ) * HO + ho) * WO + wo];
        float py = dy + (float)(2 * ho - 1 + ky);
        float px = dx + (float)(2 * wo - 1 + kx);
        float fy0 = floorf(py), fx0 = floorf(px);
        float ay = py - fy0, ax = px - fx0;
        int y0 = (int)fy0, x0 = (int)fx0;
        int y1 = y0 + 1, x1 = x0 + 1;
        bool vy0 = (unsigned)y0 < HH, vy1 = (unsigned)y1 < HH;
        bool vx0 = (unsigned)x0 < WW, vx1 = (unsigned)x1 < WW;
        float w00 = (vy0 && vx0) ? (1.f - ay) * (1.f - ax) * m : 0.f;
        float w01 = (vy0 && vx1) ? (1.f - ay) * ax * m : 0.f;
        float w10 = (vy1 && vx0) ? ay * (1.f - ax) * m : 0.f;
        float w11 = (vy1 && vx1) ? ay * ax * m : 0.f;
        int cy0 = min(max(y0, 0), HH - 1), cy1 = min(max(y1, 0), HH - 1);
        int cx0 = min(max(x0, 0), WW - 1), cx1 = min(max(x1, 0), WW - 1);
        s_cidx[e][0] = (cy0 * WW + cx0) * CC;
        s_cidx[e][1] = (cy0 * WW + cx1) * CC;
        s_cidx[e][2] = (cy1 * WW + cx0) * CC;
        s_cidx[e][3] = (cy1 * WW + cx1) * CC;
        s_w[e][0] = w00; s_w[e][1] = w01; s_w[e][2] = w10; s_w[e][3] = w11;
    }

    f32x4 acc[2][4];
#pragma unroll
    for (int i = 0; i < 2; ++i)
#pragma unroll
        for (int j = 0; j < 4; ++j) acc[i][j] = (f32x4){0.f, 0.f, 0.f, 0.f};

    const int o_base = wid * 32;         // 4 waves x 32 o
    const int l16 = lane & 15;
    const int lhi = lane >> 4;

    const unsigned short* xtb = xt + (size_t)b * (HH * WW * CC);
    const int gpx = t >> 2;              // gather pixel (0..63) = wo
    const int gcb = (t & 3) * 16;        // channel base within chunk (16 ch)

    const int cbeg = SPLIT ? chalf * 64 : 0;
    const int cend = SPLIT ? cbeg + 64 : CC;

    for (int c0 = cbeg; c0 < cend; c0 += 64) {
        for (int kp = 0; kp < KK; ++kp) {
            __syncthreads();             // (A) previous window's LDS reads complete

            // ---- dense gather: 4 corners x 16 consecutive channels (2x16B) ----
            int rec = kp * PXB + gpx;
            int4v ci = *(const int4v*)&s_cidx[rec][0];
            f32x4 wq = *(const f32x4*)&s_w[rec][0];
            const unsigned short* bp = xtb + c0 + gcb;
            short8 h00a = *(const short8*)(bp + ci.x);
            short8 h00b = *(const short8*)(bp + ci.x + 8);
            short8 h01a = *(const short8*)(bp + ci.y);
            short8 h01b = *(const short8*)(bp + ci.y + 8);
            short8 h10a = *(const short8*)(bp + ci.z);
            short8 h10b = *(const short8*)(bp + ci.z + 8);
            short8 h11a = *(const short8*)(bp + ci.w);
            short8 h11b = *(const short8*)(bp + ci.w + 8);

            // ---- weight fragments from L2-resident wprep (R9/R14-exact) ----
            const unsigned short* wb = wprep + (size_t)kp * (COUT * CC) + c0 + lhi * 8;
            short8 afr[2][2];
#pragma unroll
            for (int mr = 0; mr < 2; ++mr)
#pragma unroll
                for (int kk = 0; kk < 2; ++kk)
                    afr[mr][kk] = *(const short8*)(wb + (size_t)(o_base + mr * 16 + l16) * CC + kk * 32);

            short8 v0, v1;
#pragma unroll
            for (int j = 0; j < 8; ++j) {
                float val = wq.x * b2f((unsigned short)h00a[j]) + wq.y * b2f((unsigned short)h01a[j])
                          + wq.z * b2f((unsigned short)h10a[j]) + wq.w * b2f((unsigned short)h11a[j]);
                v0[j] = (short)bf16bits(val);
            }
#pragma unroll
            for (int j = 0; j < 8; ++j) {
                float val = wq.x * b2f((unsigned short)h00b[j]) + wq.y * b2f((unsigned short)h01b[j])
                          + wq.z * b2f((unsigned short)h10b[j]) + wq.w * b2f((unsigned short)h11b[j]);
                v1[j] = (short)bf16bits(val);
            }
            *(short8*)&s_val[gpx][gcb] = v0;
            *(short8*)&s_val[gpx][gcb + 8] = v1;

            __syncthreads();             // (B) val tile visible

#pragma unroll
            for (int nr = 0; nr < 4; ++nr) {
                short8 bfr[2];
#pragma unroll
                for (int kk = 0; kk < 2; ++kk)
                    bfr[kk] = *(const short8*)&s_val[nr * 16 + l16][kk * 32 + lhi * 8];
#pragma unroll
                for (int mr = 0; mr < 2; ++mr)
#pragma unroll
                    for (int kk = 0; kk < 2; ++kk)
                        acc[mr][nr] = __builtin_amdgcn_mfma_f32_16x16x32_bf16(
                            afr[mr][kk], bfr[kk], acc[mr][nr], 0, 0, 0);
            }
        }
    }

    // ---- epilogue ----
    float* ob = out + ((size_t)b * COUT) * (HO * WO) + (size_t)ho * WO;
    if (!SPLIT) {
#pragma unroll
        for (int mr = 0; mr < 2; ++mr) {
            int o_r = o_base + mr * 16 + lhi * 4;
#pragma unroll
            for (int r = 0; r < 4; ++r) {
                int o = o_r + r;
                float bs = bias[o];
#pragma unroll
                for (int nr = 0; nr < 4; ++nr) {
                    int wo = nr * 16 + l16;
                    ob[(size_t)o * (HO * WO) + wo] = acc[mr][nr][r] + bs;
                }
            }
        }
        return;
    }

    const int pair = blk & 511;
    // 1) publish own raw partial
    if (chalf == 1) {
        float* pb = part1 + (size_t)pair * 8192;
#pragma unroll
        for (int mr = 0; mr < 2; ++mr)
#pragma unroll
            for (int nr = 0; nr < 4; ++nr)
                *(f32x4*)&pb[(size_t)(mr * 4 + nr) * 1024 + t * 4] = acc[mr][nr];
    } else {
#pragma unroll
        for (int mr = 0; mr < 2; ++mr) {
            int o_r = o_base + mr * 16 + lhi * 4;
#pragma unroll
            for (int r = 0; r < 4; ++r) {
                int o = o_r + r;
#pragma unroll
                for (int nr = 0; nr < 4; ++nr) {
                    int wo = nr * 16 + l16;
                    ob[(size_t)o * (HO * WO) + wo] = acc[mr][nr][r];   // raw, no bias
                }
            }
        }
    }
    __threadfence();                       // release: partial visible device-wide
    if (t == 0) s_last = atomicAdd(&cnt[pair], 1);
    __syncthreads();
    if (s_last != 1) return;               // first finisher exits

    __threadfence();                       // acquire: partner's partial visible
    // 2) merge: (partner + own), identical association both ways (fp add commutes)
    if (chalf == 0) {
        const float* pb = part1 + (size_t)pair * 8192;
#pragma unroll
        for (int mr = 0; mr < 2; ++mr)
#pragma unroll
            for (int nr = 0; nr < 4; ++nr) {
                f32x4 p = *(const f32x4*)&pb[(size_t)(mr * 4 + nr) * 1024 + t * 4];
                acc[mr][nr] = p + acc[mr][nr];
            }
    } else {
#pragma unroll
        for (int mr = 0; mr < 2; ++mr) {
            int o_r = o_base + mr * 16 + lhi * 4;
#pragma unroll
            for (int r = 0; r < 4; ++r) {
                int o = o_r + r;
#pragma unroll
                for (int nr = 0; nr < 4; ++nr) {
                    int wo = nr * 16 + l16;
                    acc[mr][nr][r] = ob[(size_t)o * (HO * WO) + wo] + acc[mr][nr][r];
                }
            }
        }
    }
    // 3) final store with bias
#pragma unroll
    for (int mr = 0; mr < 2; ++mr) {
        int o_r = o_base + mr * 16 + lhi * 4;
#pragma unroll
        for (int r = 0; r < 4; ++r) {
            int o = o_r + r;
            float bs = bias[o];
#pragma unroll
            for (int nr = 0; nr < 4; ++nr) {
                int wo = nr * 16 + l16;
                ob[(size_t)o * (HO * WO) + wo] = acc[mr][nr][r] + bs;
            }
        }
    }
}

// ---------------- R6 fallback (verbatim), used only if d_ws is too small ----------------
#define PXB6 32
#define NREC6 (KK * PXB6)
template <bool PREP>
__global__ __launch_bounds__(256, 4)
void dcn6_kernel(const float* __restrict__ x, const float* __restrict__ offset,
                 const float* __restrict__ mask, const float* __restrict__ weight,
                 const unsigned short* __restrict__ wprep,
                 const float* __restrict__ bias, float* __restrict__ out) {
    const int blk = blockIdx.x;
    const int b = blk & 7;
    const int rr = blk >> 3;
    const int ho = rr >> 1;
    const int px0 = (rr & 1) * PXB6;
    const int t = threadIdx.x;
    const int lane = t & 63;
    const int wid = t >> 6;

    __shared__ int            s_off[NREC6][2];
    __shared__ float          s_wq[NREC6][4];
    __shared__ unsigned short s_wt6[COUT][40];
    __shared__ unsigned short s_val6[PXB6][40];

    for (int e = t; e < NREC6; e += 256) {
        int kp = e >> 5;
        int wo = px0 + (e & 31);
        int ky = kp / 3, kx = kp - ky * 3;
        float dy = offset[(((size_t)b * 18 + 2 * kp    ) * HO + ho) * WO + wo];
        float dx = offset[(((size_t)b * 18 + 2 * kp + 1) * HO + ho) * WO + wo];
        float m  = mask  [(((size_t)b * 9  + kp        ) * HO + ho) * WO + wo];
        float py = dy + (float)(2 * ho - 1 + ky);
        float px = dx + (float)(2 * wo - 1 + kx);
        float fy0 = floorf(py), fx0 = floorf(px);
        float ay = py - fy0, ax = px - fx0;
        int y0 = (int)fy0, x0 = (int)fx0;
        int y1 = y0 + 1, x1 = x0 + 1;
        bool vy0 = (unsigned)y0 < HH, vy1 = (unsigned)y1 < HH;
        bool vx0 = (unsigned)x0 < WW, vx1 = (unsigned)x1 < WW;
        float w00 = (vy0 && vx0) ? (1.f - ay) * (1.f - ax) * m : 0.f;
        float w01 = (vy0 && vx1) ? (1.f - ay) * ax * m : 0.f;
        float w10 = (vy1 && vx0) ? ay * (1.f - ax) * m : 0.f;
        float w11 = (vy1 && vx1) ? ay * ax * m : 0.f;
        int bx = min(max(x0, 0), WW - 2);
        float wA0 = (x0 == bx     ? w00 : 0.f) + (x1 == bx     ? w01 : 0.f);
        float wB0 = (x0 == bx + 1 ? w00 : 0.f) + (x1 == bx + 1 ? w01 : 0.f);
        float wA1 = (x0 == bx     ? w10 : 0.f) + (x1 == bx     ? w11 : 0.f);
        float wB1 = (x0 == bx + 1 ? w10 : 0.f) + (x1 == bx + 1 ? w11 : 0.f);
        int cy0 = min(max(y0, 0), HH - 1), cy1 = min(max(y1, 0), HH - 1);
        s_off[e][0] = cy0 * WW + bx;
        s_off[e][1] = cy1 * WW + bx;
        s_wq[e][0] = wA0; s_wq[e][1] = wB0; s_wq[e][2] = wA1; s_wq[e][3] = wB1;
    }

    f32x4 acc[2][2];
#pragma unroll
    for (int i = 0; i < 2; ++i)
#pragma unroll
        for (int j = 0; j < 2; ++j) acc[i][j] = (f32x4){0.f, 0.f, 0.f, 0.f};

    const int o_base = wid * 32;
    const int l16 = lane & 15;
    const int lhi = lane >> 4;
    const float* xb = x + (size_t)b * CC * HH * WW;
    const int gpx = t & 31;
    const int gcg = t >> 5;

    for (int c0 = 0; c0 < CC; c0 += 32) {
        for (int kp = 0; kp < KK; ++kp) {
            __syncthreads();
            if (PREP) {
                const unsigned short* src =
                    wprep + ((size_t)kp * COUT + (t >> 1)) * CC + c0 + (t & 1) * 16;
                short8 w0 = *(const short8*)(src);
                short8 w1 = *(const short8*)(src + 8);
                *(short8*)&s_wt6[t >> 1][(t & 1) * 16] = w0;
                *(short8*)&s_wt6[t >> 1][(t & 1) * 16 + 8] = w1;
            } else {
                int o = t & 127;
                int clb = (t >> 7) * 16;
                const float* wp = weight + (size_t)o * (CC * KK) + (size_t)(c0 + clb) * KK + kp;
                short8 w0, w1;
#pragma unroll
                for (int j = 0; j < 8; ++j) w0[j] = (short)bf16bits(wp[j * KK]);
#pragma unroll
                for (int j = 0; j < 8; ++j) w1[j] = (short)bf16bits(wp[(8 + j) * KK]);
                *(short8*)&s_wt6[o][clb] = w0;
                *(short8*)&s_wt6[o][clb + 8] = w1;
            }
            {
                int rec = kp * PXB6 + gpx;
                int o0 = s_off[rec][0], o1 = s_off[rec][1];
                f32x4 wq = *(const f32x4*)&s_wq[rec][0];
                const float* pl = xb + (size_t)(c0 + gcg * 4) * (HH * WW);
                short4v v;
#pragma unroll
                for (int j = 0; j < 4; ++j) {
                    const float* p = pl + (size_t)j * (HH * WW);
                    float2 f0 = *(const float2*)(p + o0);
                    float2 f1 = *(const float2*)(p + o1);
                    float val = wq.x * f0.x + wq.y * f0.y + wq.z * f1.x + wq.w * f1.y;
                    v[j] = (short)bf16bits(val);
                }
                *(short4v*)&s_val6[gpx][gcg * 4] = v;
            }
            __syncthreads();
            short8 afr[2];
#pragma unroll
            for (int mr = 0; mr < 2; ++mr)
                afr[mr] = *(const short8*)&s_wt6[o_base + mr * 16 + l16][lhi * 8];
            short8 bfr[2];
#pragma unroll
            for (int nr = 0; nr < 2; ++nr)
                bfr[nr] = *(const short8*)&s_val6[nr * 16 + l16][lhi * 8];
#pragma unroll
            for (int mr = 0; mr < 2; ++mr)
#pragma unroll
                for (int nr = 0; nr < 2; ++nr)
                    acc[mr][nr] = __builtin_amdgcn_mfma_f32_16x16x32_bf16(
                        afr[mr], bfr[nr], acc[mr][nr], 0, 0, 0);
        }
    }

    float* ob = out + ((size_t)b * COUT) * (HO * WO) + (size_t)ho * WO;
#pragma unroll
    for (int mr = 0; mr < 2; ++mr) {
        int o_r = o_base + mr * 16 + lhi * 4;
#pragma unroll
        for (int r = 0; r < 4; ++r) {
            int o = o_r + r;
            float bs = bias[o];
#pragma unroll
            for (int nr = 0; nr < 2; ++nr) {
                int wo = px0 + nr * 16 + l16;
                ob[(size_t)o * (HO * WO) + wo] = acc[mr][nr][r] + bs;
            }
        }
    }
}

extern "C" void kernel_launch(void* const* d_in, const int* in_sizes, int n_in,
                              void* d_out, int out_size, void* d_ws, size_t ws_size,
                              hipStream_t stream) {
    (void)in_sizes; (void)n_in; (void)out_size;
    const float* x      = (const float*)d_in[0];
    const float* offset = (const float*)d_in[1];
    const float* mask   = (const float*)d_in[2];
    const float* weight = (const float*)d_in[3];
    const float* bias   = (const float*)d_in[4];
    float* out = (float*)d_out;

    const size_t wbytes  = (size_t)KK * COUT * CC * sizeof(unsigned short);   // 294912
    const size_t cntoff  = (size_t)512 << 10;                                 // 512 KB (in wp/xt gap)
    const size_t xtoff   = (size_t)1 << 20;                                   // 1 MB
    const size_t xtbytes = (size_t)8 * HH * WW * CC * sizeof(unsigned short); // 32 MB
    const size_t p1off   = xtoff + xtbytes;                                   // 34,603,008
    const size_t p1bytes = (size_t)512 * 8192 * sizeof(float);                // 16,777,216

    if (ws_size >= p1off + p1bytes) {      // same gate as proven R14 path
        unsigned short* wp  = (unsigned short*)d_ws;
        int* cnt            = (int*)((char*)d_ws + cntoff);
        unsigned short* xtp = (unsigned short*)((char*)d_ws + xtoff);
        float* p1           = (float*)((char*)d_ws + p1off);
        prep_kernel<<<dim3(1601), dim3(256), 0, stream>>>(x, xtp, weight, wp, cnt);
        dcn16_kernel<true><<<dim3(1024), dim3(256), 0, stream>>>(xtp, offset, mask, wp, bias, out, p1, cnt);
    } else if (ws_size >= p1off) {
        unsigned short* wp  = (unsigned short*)d_ws;
        int* cnt            = (int*)((char*)d_ws + cntoff);
        unsigned short* xtp = (unsigned short*)((char*)d_ws + xtoff);
        prep_kernel<<<dim3(1601), dim3(256), 0, stream>>>(x, xtp, weight, wp, cnt);
        dcn16_kernel<false><<<dim3(512), dim3(256), 0, stream>>>(xtp, offset, mask, wp, bias, out, nullptr, cnt);
    } else {
        dcn6_kernel<false><<<dim3(1024), dim3(256), 0, stream>>>(x, offset, mask, weight, nullptr, bias, out);
    }
}

// Round 17
// 66.074 us; speedup vs baseline: 3.5772x; 3.5772x over previous
//
#include <hip/hip_runtime.h>
#include <hip/hip_bf16.h>

typedef __attribute__((ext_vector_type(8))) short short8;
typedef __attribute__((ext_vector_type(4))) short short4v;
typedef __attribute__((ext_vector_type(4))) float f32x4;
typedef __attribute__((ext_vector_type(4))) int int4v;
typedef unsigned long long u64;

#define HH 128
#define WW 128
#define CC 128
#define COUT 128
#define HO 64
#define WO 64
#define KK 9
#define PXB 64
#define NREC (KK * PXB)   /* 576 */

__device__ __forceinline__ unsigned short bf16bits(float f) {
    union { float f; unsigned u; } u; u.f = f;
    unsigned r = u.u + 0x7fffu + ((u.u >> 16) & 1u);
    return (unsigned short)(r >> 16);
}
__device__ __forceinline__ float b2f(unsigned short h) {
    union { unsigned u; float f; } v; v.u = ((unsigned)h) << 16; return v.f;
}

// Fused prep: blocks [0,1024): x NCHW f32 -> xt NHWC bf16 (one block per (b,y));
//             blocks [1024,1600): weight [Cout][C][9] f32 -> wp [9][Cout][C] bf16.
__global__ __launch_bounds__(256, 4)
void prep_kernel(const float* __restrict__ x, unsigned short* __restrict__ xt,
                 const float* __restrict__ w, unsigned short* __restrict__ wp) {
    const int blk = blockIdx.x;
    const int t = threadIdx.x;
    __shared__ unsigned short tile[128][132];

    if (blk < 1024) {
        const int b = blk >> 7;
        const int y = blk & 127;
        const float* src = x + (((size_t)b * CC) * HH + y) * WW;
#pragma unroll 8
        for (int c0 = 0; c0 < CC; c0 += 2) {
            int c = c0 + (t >> 7);
            int xx = t & 127;
            tile[xx][c] = bf16bits(src[(size_t)c * (HH * WW) + xx]);
        }
        __syncthreads();
        unsigned short* dst = xt + (((size_t)b * HH + y) * WW) * CC;
#pragma unroll
        for (int it = 0; it < 4; ++it) {
            int lin = it * 256 + t;
            int xx = lin >> 3;
            int cb = (lin & 7) * 16;
            const u64* lp = (const u64*)&tile[xx][cb];
            u64* op = (u64*)(dst + (size_t)xx * CC + cb);
            op[0] = lp[0]; op[1] = lp[1]; op[2] = lp[2]; op[3] = lp[3];
        }
    } else {
        int i = (blk - 1024) * 256 + t;
        if (i < KK * COUT * CC) {
            int kp = i / (COUT * CC);
            int r = i - kp * (COUT * CC);
            int o = r >> 7;
            int c = r & 127;
            wp[i] = bf16bits(w[((size_t)o * CC + c) * KK + kp]);
        }
    }
}

// out += part1   (R14-verbatim)
__global__ __launch_bounds__(256, 8)
void add_kernel(float* __restrict__ out, const float* __restrict__ p1) {
    size_t i = ((size_t)blockIdx.x * 256 + threadIdx.x) * 4;
    const size_t N = (size_t)8 * COUT * HO * WO;
    const size_t STR = (size_t)2048 * 256 * 4;
    for (; i < N; i += STR) {
        f32x4 a = *(const f32x4*)(out + i);
        f32x4 b = *(const f32x4*)(p1 + i);
        a = a + b;
        *(f32x4*)(out + i) = a;
    }
}

// Main kernel: R14 VERBATIM (proven 41.5 us). Split-C, 9 two-barrier windows,
// PXB=64 full row, weights direct-to-register from L2-resident wprep,
// non-atomic epilogue: chalf0 -> out (+bias), chalf1 -> part1 (raw).
template <bool SPLIT>
__global__ __launch_bounds__(256, 4)
void dcn14_kernel(const unsigned short* __restrict__ xt, const float* __restrict__ offset,
                  const float* __restrict__ mask, const unsigned short* __restrict__ wprep,
                  const float* __restrict__ bias, float* __restrict__ out,
                  float* __restrict__ part1) {
    const int blk = blockIdx.x;
    const int b = blk & 7;               // XCD i streams batch image i
    const int ho = (blk >> 3) & 63;
    const int chalf = SPLIT ? (blk >> 9) : 0;
    const int t = threadIdx.x;
    const int lane = t & 63;
    const int wid = t >> 6;

    __shared__ int            s_cidx[NREC][4];   // corner offsets, pre-scaled by CC
    __shared__ float          s_w[NREC][4];      // bilinear weights * mask (0 if OOB)
    __shared__ unsigned short s_val[PXB][72];    // bf16 val tile [px 64][c64 pad72]

    // ---- per-(kp,wo) sampling records (same math as R1/R5/R7/R9/R14) ----
    for (int e = t; e < NREC; e += 256) {
        int kp = e >> 6;
        int wo = e & 63;
        int ky = kp / 3, kx = kp - ky * 3;
        float dy = offset[(((size_t)b * 18 + 2 * kp    ) * HO + ho) * WO + wo];
        float dx = offset[(((size_t)b * 18 + 2 * kp + 1) * HO + ho) * WO + wo];
        float m  = mask  [(((size_t)b * 9  + kp        ) * HO + ho) * WO + wo];
        float py = dy + (float)(2 * ho - 1 + ky);
        float px = dx + (float)(2 * wo - 1 + kx);
        float fy0 = floorf(py), fx0 = floorf(px);
        float ay = py - fy0, ax = px - fx0;
        int y0 = (int)fy0, x0 = (int)fx0;
        int y1 = y0 + 1, x1 = x0 + 1;
        bool vy0 = (unsigned)y0 < HH, vy1 = (unsigned)y1 < HH;
        bool vx0 = (unsigned)x0 < WW, vx1 = (unsigned)x1 < WW;
        float w00 = (vy0 && vx0) ? (1.f - ay) * (1.f - ax) * m : 0.f;
        float w01 = (vy0 && vx1) ? (1.f - ay) * ax * m : 0.f;
        float w10 = (vy1 && vx0) ? ay * (1.f - ax) * m : 0.f;
        float w11 = (vy1 && vx1) ? ay * ax * m : 0.f;
        int cy0 = min(max(y0, 0), HH - 1), cy1 = min(max(y1, 0), HH - 1);
        int cx0 = min(max(x0, 0), WW - 1), cx1 = min(max(x1, 0), WW - 1);
        s_cidx[e][0] = (cy0 * WW + cx0) * CC;
        s_cidx[e][1] = (cy0 * WW + cx1) * CC;
        s_cidx[e][2] = (cy1 * WW + cx0) * CC;
        s_cidx[e][3] = (cy1 * WW + cx1) * CC;
        s_w[e][0] = w00; s_w[e][1] = w01; s_w[e][2] = w10; s_w[e][3] = w11;
    }

    f32x4 acc[2][4];
#pragma unroll
    for (int i = 0; i < 2; ++i)
#pragma unroll
        for (int j = 0; j < 4; ++j) acc[i][j] = (f32x4){0.f, 0.f, 0.f, 0.f};

    const int o_base = wid * 32;         // 4 waves x 32 o
    const int l16 = lane & 15;
    const int lhi = lane >> 4;

    const unsigned short* xtb = xt + (size_t)b * (HH * WW * CC);
    const int gpx = t >> 2;              // gather pixel (0..63) = wo
    const int gcb = (t & 3) * 16;        // channel base within chunk (16 ch)

    const int cbeg = SPLIT ? chalf * 64 : 0;
    const int cend = SPLIT ? cbeg + 64 : CC;

    for (int c0 = cbeg; c0 < cend; c0 += 64) {
        for (int kp = 0; kp < KK; ++kp) {
            __syncthreads();             // (A) previous window's LDS reads complete

            // ---- dense gather: 4 corners x 16 consecutive channels (2x16B) ----
            int rec = kp * PXB + gpx;
            int4v ci = *(const int4v*)&s_cidx[rec][0];
            f32x4 wq = *(const f32x4*)&s_w[rec][0];
            const unsigned short* bp = xtb + c0 + gcb;
            short8 h00a = *(const short8*)(bp + ci.x);
            short8 h00b = *(const short8*)(bp + ci.x + 8);
            short8 h01a = *(const short8*)(bp + ci.y);
            short8 h01b = *(const short8*)(bp + ci.y + 8);
            short8 h10a = *(const short8*)(bp + ci.z);
            short8 h10b = *(const short8*)(bp + ci.z + 8);
            short8 h11a = *(const short8*)(bp + ci.w);
            short8 h11b = *(const short8*)(bp + ci.w + 8);

            // ---- weight fragments from L2-resident wprep (R9/R14-exact) ----
            const unsigned short* wb = wprep + (size_t)kp * (COUT * CC) + c0 + lhi * 8;
            short8 afr[2][2];
#pragma unroll
            for (int mr = 0; mr < 2; ++mr)
#pragma unroll
                for (int kk = 0; kk < 2; ++kk)
                    afr[mr][kk] = *(const short8*)(wb + (size_t)(o_base + mr * 16 + l16) * CC + kk * 32);

            short8 v0, v1;
#pragma unroll
            for (int j = 0; j < 8; ++j) {
                float val = wq.x * b2f((unsigned short)h00a[j]) + wq.y * b2f((unsigned short)h01a[j])
                          + wq.z * b2f((unsigned short)h10a[j]) + wq.w * b2f((unsigned short)h11a[j]);
                v0[j] = (short)bf16bits(val);
            }
#pragma unroll
            for (int j = 0; j < 8; ++j) {
                float val = wq.x * b2f((unsigned short)h00b[j]) + wq.y * b2f((unsigned short)h01b[j])
                          + wq.z * b2f((unsigned short)h10b[j]) + wq.w * b2f((unsigned short)h11b[j]);
                v1[j] = (short)bf16bits(val);
            }
            *(short8*)&s_val[gpx][gcb] = v0;
            *(short8*)&s_val[gpx][gcb + 8] = v1;

            __syncthreads();             // (B) val tile visible

#pragma unroll
            for (int nr = 0; nr < 4; ++nr) {
                short8 bfr[2];
#pragma unroll
                for (int kk = 0; kk < 2; ++kk)
                    bfr[kk] = *(const short8*)&s_val[nr * 16 + l16][kk * 32 + lhi * 8];
#pragma unroll
                for (int mr = 0; mr < 2; ++mr)
#pragma unroll
                    for (int kk = 0; kk < 2; ++kk)
                        acc[mr][nr] = __builtin_amdgcn_mfma_f32_16x16x32_bf16(
                            afr[mr][kk], bfr[kk], acc[mr][nr], 0, 0, 0);
            }
        }
    }

    // ---- epilogue (R14-verbatim) ----
    float* dst = (SPLIT && chalf == 1) ? part1 : out;
    const bool addb = (!SPLIT) || (chalf == 0);
    float* ob = dst + ((size_t)b * COUT) * (HO * WO) + (size_t)ho * WO;
#pragma unroll
    for (int mr = 0; mr < 2; ++mr) {
        int o_r = o_base + mr * 16 + lhi * 4;
#pragma unroll
        for (int r = 0; r < 4; ++r) {
            int o = o_r + r;
            float bs = addb ? bias[o] : 0.f;
#pragma unroll
            for (int nr = 0; nr < 4; ++nr) {
                int wo = nr * 16 + l16;
                ob[(size_t)o * (HO * WO) + wo] = acc[mr][nr][r] + bs;
            }
        }
    }
}

// ---------------- R6 fallback (verbatim), used only if d_ws is too small ----------------
#define PXB6 32
#define NREC6 (KK * PXB6)
template <bool PREP>
__global__ __launch_bounds__(256, 4)
void dcn6_kernel(const float* __restrict__ x, const float* __restrict__ offset,
                 const float* __restrict__ mask, const float* __restrict__ weight,
                 const unsigned short* __restrict__ wprep,
                 const float* __restrict__ bias, float* __restrict__ out) {
    const int blk = blockIdx.x;
    const int b = blk & 7;
    const int rr = blk >> 3;
    const int ho = rr >> 1;
    const int px0 = (rr & 1) * PXB6;
    const int t = threadIdx.x;
    const int lane = t & 63;
    const int wid = t >> 6;

    __shared__ int            s_off[NREC6][2];
    __shared__ float          s_wq[NREC6][4];
    __shared__ unsigned short s_wt6[COUT][40];
    __shared__ unsigned short s_val6[PXB6][40];

    for (int e = t; e < NREC6; e += 256) {
        int kp = e >> 5;
        int wo = px0 + (e & 31);
        int ky = kp / 3, kx = kp - ky * 3;
        float dy = offset[(((size_t)b * 18 + 2 * kp    ) * HO + ho) * WO + wo];
        float dx = offset[(((size_t)b * 18 + 2 * kp + 1) * HO + ho) * WO + wo];
        float m  = mask  [(((size_t)b * 9  + kp        ) * HO + ho) * WO + wo];
        float py = dy + (float)(2 * ho - 1 + ky);
        float px = dx + (float)(2 * wo - 1 + kx);
        float fy0 = floorf(py), fx0 = floorf(px);
        float ay = py - fy0, ax = px - fx0;
        int y0 = (int)fy0, x0 = (int)fx0;
        int y1 = y0 + 1, x1 = x0 + 1;
        bool vy0 = (unsigned)y0 < HH, vy1 = (unsigned)y1 < HH;
        bool vx0 = (unsigned)x0 < WW, vx1 = (unsigned)x1 < WW;
        float w00 = (vy0 && vx0) ? (1.f - ay) * (1.f - ax) * m : 0.f;
        float w01 = (vy0 && vx1) ? (1.f - ay) * ax * m : 0.f;
        float w10 = (vy1 && vx0) ? ay * (1.f - ax) * m : 0.f;
        float w11 = (vy1 && vx1) ? ay * ax * m : 0.f;
        int bx = min(max(x0, 0), WW - 2);
        float wA0 = (x0 == bx     ? w00 : 0.f) + (x1 == bx     ? w01 : 0.f);
        float wB0 = (x0 == bx + 1 ? w00 : 0.f) + (x1 == bx + 1 ? w01 : 0.f);
        float wA1 = (x0 == bx     ? w10 : 0.f) + (x1 == bx     ? w11 : 0.f);
        float wB1 = (x0 == bx + 1 ? w10 : 0.f) + (x1 == bx + 1 ? w11 : 0.f);
        int cy0 = min(max(y0, 0), HH - 1), cy1 = min(max(y1, 0), HH - 1);
        s_off[e][0] = cy0 * WW + bx;
        s_off[e][1] = cy1 * WW + bx;
        s_wq[e][0] = wA0; s_wq[e][1] = wB0; s_wq[e][2] = wA1; s_wq[e][3] = wB1;
    }

    f32x4 acc[2][2];
#pragma unroll
    for (int i = 0; i < 2; ++i)
#pragma unroll
        for (int j = 0; j < 2; ++j) acc[i][j] = (f32x4){0.f, 0.f, 0.f, 0.f};

    const int o_base = wid * 32;
    const int l16 = lane & 15;
    const int lhi = lane >> 4;
    const float* xb = x + (size_t)b * CC * HH * WW;
    const int gpx = t & 31;
    const int gcg = t >> 5;

    for (int c0 = 0; c0 < CC; c0 += 32) {
        for (int kp = 0; kp < KK; ++kp) {
            __syncthreads();
            if (PREP) {
                const unsigned short* src =
                    wprep + ((size_t)kp * COUT + (t >> 1)) * CC + c0 + (t & 1) * 16;
                short8 w0 = *(const short8*)(src);
                short8 w1 = *(const short8*)(src + 8);
                *(short8*)&s_wt6[t >> 1][(t & 1) * 16] = w0;
                *(short8*)&s_wt6[t >> 1][(t & 1) * 16 + 8] = w1;
            } else {
                int o = t & 127;
                int clb = (t >> 7) * 16;
                const float* wp = weight + (size_t)o * (CC * KK) + (size_t)(c0 + clb) * KK + kp;
                short8 w0, w1;
#pragma unroll
                for (int j = 0; j < 8; ++j) w0[j] = (short)bf16bits(wp[j * KK]);
#pragma unroll
                for (int j = 0; j < 8; ++j) w1[j] = (short)bf16bits(wp[(8 + j) * KK]);
                *(short8*)&s_wt6[o][clb] = w0;
                *(short8*)&s_wt6[o][clb + 8] = w1;
            }
            {
                int rec = kp * PXB6 + gpx;
                int o0 = s_off[rec][0], o1 = s_off[rec][1];
                f32x4 wq = *(const f32x4*)&s_wq[rec][0];
                const float* pl = xb + (size_t)(c0 + gcg * 4) * (HH * WW);
                short4v v;
#pragma unroll
                for (int j = 0; j < 4; ++j) {
                    const float* p = pl + (size_t)j * (HH * WW);
                    float2 f0 = *(const float2*)(p + o0);
                    float2 f1 = *(const float2*)(p + o1);
                    float val = wq.x * f0.x + wq.y * f0.y + wq.z * f1.x + wq.w * f1.y;
                    v[j] = (short)bf16bits(val);
                }
                *(short4v*)&s_val6[gpx][gcg * 4] = v;
            }
            __syncthreads();
            short8 afr[2];
#pragma unroll
            for (int mr = 0; mr < 2; ++mr)
                afr[mr] = *(const short8*)&s_wt6[o_base + mr * 16 + l16][lhi * 8];
            short8 bfr[2];
#pragma unroll
            for (int nr = 0; nr < 2; ++nr)
                bfr[nr] = *(const short8*)&s_val6[nr * 16 + l16][lhi * 8];
#pragma unroll
            for (int mr = 0; mr < 2; ++mr)
#pragma unroll
                for (int nr = 0; nr < 2; ++nr)
                    acc[mr][nr] = __builtin_amdgcn_mfma_f32_16x16x32_bf16(
                        afr[mr], bfr[nr], acc[mr][nr], 0, 0, 0);
        }
    }

    float* ob = out + ((size_t)b * COUT) * (HO * WO) + (size_t)ho * WO;
#pragma unroll
    for (int mr = 0; mr < 2; ++mr) {
        int o_r = o_base + mr * 16 + lhi * 4;
#pragma unroll
        for (int r = 0; r < 4; ++r) {
            int o = o_r + r;
            float bs = bias[o];
#pragma unroll
            for (int nr = 0; nr < 2; ++nr) {
                int wo = px0 + nr * 16 + l16;
                ob[(size_t)o * (HO * WO) + wo] = acc[mr][nr][r] + bs;
            }
        }
    }
}

extern "C" void kernel_launch(void* const* d_in, const int* in_sizes, int n_in,
                              void* d_out, int out_size, void* d_ws, size_t ws_size,
                              hipStream_t stream) {
    (void)in_sizes; (void)n_in; (void)out_size;
    const float* x      = (const float*)d_in[0];
    const float* offset = (const float*)d_in[1];
    const float* mask   = (const float*)d_in[2];
    const float* weight = (const float*)d_in[3];
    const float* bias   = (const float*)d_in[4];
    float* out = (float*)d_out;

    const size_t wbytes  = (size_t)KK * COUT * CC * sizeof(unsigned short);   // 294912
    const size_t xtoff   = (size_t)1 << 20;                                   // 1 MB
    const size_t xtbytes = (size_t)8 * HH * WW * CC * sizeof(unsigned short); // 32 MB
    const size_t p1off   = xtoff + xtbytes;                                   // 34,603,008
    const size_t p1bytes = (size_t)8 * COUT * HO * WO * sizeof(float);        // 16.8 MB

    if (ws_size >= p1off + p1bytes) {
        unsigned short* wp  = (unsigned short*)d_ws;
        unsigned short* xtp = (unsigned short*)((char*)d_ws + xtoff);
        float* p1           = (float*)((char*)d_ws + p1off);
        prep_kernel<<<dim3(1600), dim3(256), 0, stream>>>(x, xtp, weight, wp);
        dcn14_kernel<true><<<dim3(1024), dim3(256), 0, stream>>>(xtp, offset, mask, wp, bias, out, p1);
        add_kernel<<<dim3(2048), dim3(256), 0, stream>>>(out, p1);
    } else if (ws_size >= xtoff + xtbytes) {
        unsigned short* wp  = (unsigned short*)d_ws;
        unsigned short* xtp = (unsigned short*)((char*)d_ws + xtoff);
        prep_kernel<<<dim3(1600), dim3(256), 0, stream>>>(x, xtp, weight, wp);
        dcn14_kernel<false><<<dim3(512), dim3(256), 0, stream>>>(xtp, offset, mask, wp, bias, out, nullptr);
    } else {
        dcn6_kernel<false><<<dim3(1024), dim3(256), 0, stream>>>(x, offset, mask, weight, nullptr, bias, out);
    }
}

// Round 18
// 59.581 us; speedup vs baseline: 3.9670x; 1.1090x over previous
//
#include <hip/hip_runtime.h>
#include <hip/hip_bf16.h>

typedef __attribute__((ext_vector_type(8))) short short8;
typedef __attribute__((ext_vector_type(4))) short short4v;
typedef __attribute__((ext_vector_type(4))) float f32x4;
typedef __attribute__((ext_vector_type(4))) int int4v;
typedef unsigned long long u64;

#define HH 128
#define WW 128
#define CC 128
#define COUT 128
#define HO 64
#define WO 64
#define KK 9
#define PXB 64
#define NREC (KK * PXB)   /* 576 */

__device__ __forceinline__ unsigned short bf16bits(float f) {
    union { float f; unsigned u; } u; u.f = f;
    unsigned r = u.u + 0x7fffu + ((u.u >> 16) & 1u);
    return (unsigned short)(r >> 16);
}
__device__ __forceinline__ float b2f(unsigned short h) {
    union { unsigned u; float f; } v; v.u = ((unsigned)h) << 16; return v.f;
}

// Fused prep:
//  blocks [0,1024): x NCHW f32 -> xt NHWC bf16 (one block per (b,y));
//  blocks [1024,1600): weight -> wp in MFMA-FRAGMENT-LINEAR layout:
//    wp[ ((kp*2 + chalf)*4 + ot)*2048 + (mr*2+kk)*512 + lane*8 + j ]
//      = bf16( w[o][c][kp] ), o = ot*32 + mr*16 + (lane&15),
//                             c = chalf*64 + kk*32 + (lane>>4)*8 + j.
//    A wave's 4 fragment loads are then lane-contiguous 16B (fully coalesced).
__global__ __launch_bounds__(256, 4)
void prep_kernel(const float* __restrict__ x, unsigned short* __restrict__ xt,
                 const float* __restrict__ w, unsigned short* __restrict__ wp) {
    const int blk = blockIdx.x;
    const int t = threadIdx.x;
    __shared__ unsigned short tile[128][132];

    if (blk < 1024) {
        const int b = blk >> 7;
        const int y = blk & 127;
        const float* src = x + (((size_t)b * CC) * HH + y) * WW;
#pragma unroll 8
        for (int c0 = 0; c0 < CC; c0 += 2) {
            int c = c0 + (t >> 7);
            int xx = t & 127;
            tile[xx][c] = bf16bits(src[(size_t)c * (HH * WW) + xx]);
        }
        __syncthreads();
        unsigned short* dst = xt + (((size_t)b * HH + y) * WW) * CC;
#pragma unroll
        for (int it = 0; it < 4; ++it) {
            int lin = it * 256 + t;
            int xx = lin >> 3;
            int cb = (lin & 7) * 16;
            const u64* lp = (const u64*)&tile[xx][cb];
            u64* op = (u64*)(dst + (size_t)xx * CC + cb);
            op[0] = lp[0]; op[1] = lp[1]; op[2] = lp[2]; op[3] = lp[3];
        }
    } else {
        int i = (blk - 1024) * 256 + t;          // 0 .. 147455 exactly
        int tileid = i >> 11;                    // kp*8 + chalf*4 + ot
        int inner = i & 2047;
        int kp = tileid >> 3;
        int chalf = (tileid >> 2) & 1;
        int ot = tileid & 3;
        int mrkk = inner >> 9;                   // mr*2 + kk
        int l = (inner >> 3) & 63;
        int j = inner & 7;
        int o = ot * 32 + (mrkk >> 1) * 16 + (l & 15);
        int c = chalf * 64 + (mrkk & 1) * 32 + (l >> 4) * 8 + j;
        wp[i] = bf16bits(w[((size_t)o * CC + c) * KK + kp]);
    }
}

// out += part1   (R14-verbatim)
__global__ __launch_bounds__(256, 8)
void add_kernel(float* __restrict__ out, const float* __restrict__ p1) {
    size_t i = ((size_t)blockIdx.x * 256 + threadIdx.x) * 4;
    const size_t N = (size_t)8 * COUT * HO * WO;
    const size_t STR = (size_t)2048 * 256 * 4;
    for (; i < N; i += STR) {
        f32x4 a = *(const f32x4*)(out + i);
        f32x4 b = *(const f32x4*)(p1 + i);
        a = a + b;
        *(f32x4*)(out + i) = a;
    }
}

// Main kernel: R14/R17 window internals VERBATIM; ONLY the weight-fragment
// addressing changed to the fragment-linear wp layout (same values per
// (wave,lane,mr,kk) as R14 — pure permutation of storage).
template <bool SPLIT>
__global__ __launch_bounds__(256, 4)
void dcn18_kernel(const unsigned short* __restrict__ xt, const float* __restrict__ offset,
                  const float* __restrict__ mask, const unsigned short* __restrict__ wprep,
                  const float* __restrict__ bias, float* __restrict__ out,
                  float* __restrict__ part1) {
    const int blk = blockIdx.x;
    const int b = blk & 7;               // XCD i streams batch image i
    const int ho = (blk >> 3) & 63;
    const int chalf = SPLIT ? (blk >> 9) : 0;
    const int t = threadIdx.x;
    const int lane = t & 63;
    const int wid = t >> 6;

    __shared__ int            s_cidx[NREC][4];   // corner offsets, pre-scaled by CC
    __shared__ float          s_w[NREC][4];      // bilinear weights * mask (0 if OOB)
    __shared__ unsigned short s_val[PXB][72];    // bf16 val tile [px 64][c64 pad72]

    // ---- per-(kp,wo) sampling records (same math as R1/R5/R7/R9/R14) ----
    for (int e = t; e < NREC; e += 256) {
        int kp = e >> 6;
        int wo = e & 63;
        int ky = kp / 3, kx = kp - ky * 3;
        float dy = offset[(((size_t)b * 18 + 2 * kp    ) * HO + ho) * WO + wo];
        float dx = offset[(((size_t)b * 18 + 2 * kp + 1) * HO + ho) * WO + wo];
        float m  = mask  [(((size_t)b * 9  + kp        ) * HO + ho) * WO + wo];
        float py = dy + (float)(2 * ho - 1 + ky);
        float px = dx + (float)(2 * wo - 1 + kx);
        float fy0 = floorf(py), fx0 = floorf(px);
        float ay = py - fy0, ax = px - fx0;
        int y0 = (int)fy0, x0 = (int)fx0;
        int y1 = y0 + 1, x1 = x0 + 1;
        bool vy0 = (unsigned)y0 < HH, vy1 = (unsigned)y1 < HH;
        bool vx0 = (unsigned)x0 < WW, vx1 = (unsigned)x1 < WW;
        float w00 = (vy0 && vx0) ? (1.f - ay) * (1.f - ax) * m : 0.f;
        float w01 = (vy0 && vx1) ? (1.f - ay) * ax * m : 0.f;
        float w10 = (vy1 && vx0) ? ay * (1.f - ax) * m : 0.f;
        float w11 = (vy1 && vx1) ? ay * ax * m : 0.f;
        int cy0 = min(max(y0, 0), HH - 1), cy1 = min(max(y1, 0), HH - 1);
        int cx0 = min(max(x0, 0), WW - 1), cx1 = min(max(x1, 0), WW - 1);
        s_cidx[e][0] = (cy0 * WW + cx0) * CC;
        s_cidx[e][1] = (cy0 * WW + cx1) * CC;
        s_cidx[e][2] = (cy1 * WW + cx0) * CC;
        s_cidx[e][3] = (cy1 * WW + cx1) * CC;
        s_w[e][0] = w00; s_w[e][1] = w01; s_w[e][2] = w10; s_w[e][3] = w11;
    }

    f32x4 acc[2][4];
#pragma unroll
    for (int i = 0; i < 2; ++i)
#pragma unroll
        for (int j = 0; j < 4; ++j) acc[i][j] = (f32x4){0.f, 0.f, 0.f, 0.f};

    const int o_base = wid * 32;         // 4 waves x 32 o
    const int l16 = lane & 15;
    const int lhi = lane >> 4;

    const unsigned short* xtb = xt + (size_t)b * (HH * WW * CC);
    const int gpx = t >> 2;              // gather pixel (0..63) = wo
    const int gcb = (t & 3) * 16;        // channel base within chunk (16 ch)

    const int cbeg = SPLIT ? chalf * 64 : 0;
    const int cend = SPLIT ? cbeg + 64 : CC;

    for (int c0 = cbeg; c0 < cend; c0 += 64) {
        for (int kp = 0; kp < KK; ++kp) {
            __syncthreads();             // (A) previous window's LDS reads complete

            // ---- dense gather: 4 corners x 16 consecutive channels (2x16B) ----
            int rec = kp * PXB + gpx;
            int4v ci = *(const int4v*)&s_cidx[rec][0];
            f32x4 wq = *(const f32x4*)&s_w[rec][0];
            const unsigned short* bp = xtb + c0 + gcb;
            short8 h00a = *(const short8*)(bp + ci.x);
            short8 h00b = *(const short8*)(bp + ci.x + 8);
            short8 h01a = *(const short8*)(bp + ci.y);
            short8 h01b = *(const short8*)(bp + ci.y + 8);
            short8 h10a = *(const short8*)(bp + ci.z);
            short8 h10b = *(const short8*)(bp + ci.z + 8);
            short8 h11a = *(const short8*)(bp + ci.w);
            short8 h11b = *(const short8*)(bp + ci.w + 8);

            // ---- weight fragments: fragment-linear wp, lane-contiguous 16B ----
            const unsigned short* wb =
                wprep + ((size_t)((kp * 2 + (c0 >> 6)) * 4 + wid) << 11) + lane * 8;
            short8 afr[2][2];
#pragma unroll
            for (int mr = 0; mr < 2; ++mr)
#pragma unroll
                for (int kk = 0; kk < 2; ++kk)
                    afr[mr][kk] = *(const short8*)(wb + ((mr * 2 + kk) << 9));

            short8 v0, v1;
#pragma unroll
            for (int j = 0; j < 8; ++j) {
                float val = wq.x * b2f((unsigned short)h00a[j]) + wq.y * b2f((unsigned short)h01a[j])
                          + wq.z * b2f((unsigned short)h10a[j]) + wq.w * b2f((unsigned short)h11a[j]);
                v0[j] = (short)bf16bits(val);
            }
#pragma unroll
            for (int j = 0; j < 8; ++j) {
                float val = wq.x * b2f((unsigned short)h00b[j]) + wq.y * b2f((unsigned short)h01b[j])
                          + wq.z * b2f((unsigned short)h10b[j]) + wq.w * b2f((unsigned short)h11b[j]);
                v1[j] = (short)bf16bits(val);
            }
            *(short8*)&s_val[gpx][gcb] = v0;
            *(short8*)&s_val[gpx][gcb + 8] = v1;

            __syncthreads();             // (B) val tile visible

#pragma unroll
            for (int nr = 0; nr < 4; ++nr) {
                short8 bfr[2];
#pragma unroll
                for (int kk = 0; kk < 2; ++kk)
                    bfr[kk] = *(const short8*)&s_val[nr * 16 + l16][kk * 32 + lhi * 8];
#pragma unroll
                for (int mr = 0; mr < 2; ++mr)
#pragma unroll
                    for (int kk = 0; kk < 2; ++kk)
                        acc[mr][nr] = __builtin_amdgcn_mfma_f32_16x16x32_bf16(
                            afr[mr][kk], bfr[kk], acc[mr][nr], 0, 0, 0);
            }
        }
    }

    // ---- epilogue (R14-verbatim) ----
    float* dst = (SPLIT && chalf == 1) ? part1 : out;
    const bool addb = (!SPLIT) || (chalf == 0);
    float* ob = dst + ((size_t)b * COUT) * (HO * WO) + (size_t)ho * WO;
#pragma unroll
    for (int mr = 0; mr < 2; ++mr) {
        int o_r = o_base + mr * 16 + lhi * 4;
#pragma unroll
        for (int r = 0; r < 4; ++r) {
            int o = o_r + r;
            float bs = addb ? bias[o] : 0.f;
#pragma unroll
            for (int nr = 0; nr < 4; ++nr) {
                int wo = nr * 16 + l16;
                ob[(size_t)o * (HO * WO) + wo] = acc[mr][nr][r] + bs;
            }
        }
    }
}

// ---------------- R6 fallback (verbatim), used only if d_ws is too small ----------------
#define PXB6 32
#define NREC6 (KK * PXB6)
template <bool PREP>
__global__ __launch_bounds__(256, 4)
void dcn6_kernel(const float* __restrict__ x, const float* __restrict__ offset,
                 const float* __restrict__ mask, const float* __restrict__ weight,
                 const unsigned short* __restrict__ wprep,
                 const float* __restrict__ bias, float* __restrict__ out) {
    const int blk = blockIdx.x;
    const int b = blk & 7;
    const int rr = blk >> 3;
    const int ho = rr >> 1;
    const int px0 = (rr & 1) * PXB6;
    const int t = threadIdx.x;
    const int lane = t & 63;
    const int wid = t >> 6;

    __shared__ int            s_off[NREC6][2];
    __shared__ float          s_wq[NREC6][4];
    __shared__ unsigned short s_wt6[COUT][40];
    __shared__ unsigned short s_val6[PXB6][40];

    for (int e = t; e < NREC6; e += 256) {
        int kp = e >> 5;
        int wo = px0 + (e & 31);
        int ky = kp / 3, kx = kp - ky * 3;
        float dy = offset[(((size_t)b * 18 + 2 * kp    ) * HO + ho) * WO + wo];
        float dx = offset[(((size_t)b * 18 + 2 * kp + 1) * HO + ho) * WO + wo];
        float m  = mask  [(((size_t)b * 9  + kp        ) * HO + ho) * WO + wo];
        float py = dy + (float)(2 * ho - 1 + ky);
        float px = dx + (float)(2 * wo - 1 + kx);
        float fy0 = floorf(py), fx0 = floorf(px);
        float ay = py - fy0, ax = px - fx0;
        int y0 = (int)fy0, x0 = (int)fx0;
        int y1 = y0 + 1, x1 = x0 + 1;
        bool vy0 = (unsigned)y0 < HH, vy1 = (unsigned)y1 < HH;
        bool vx0 = (unsigned)x0 < WW, vx1 = (unsigned)x1 < WW;
        float w00 = (vy0 && vx0) ? (1.f - ay) * (1.f - ax) * m : 0.f;
        float w01 = (vy0 && vx1) ? (1.f - ay) * ax * m : 0.f;
        float w10 = (vy1 && vx0) ? ay * (1.f - ax) * m : 0.f;
        float w11 = (vy1 && vx1) ? ay * ax * m : 0.f;
        int bx = min(max(x0, 0), WW - 2);
        float wA0 = (x0 == bx     ? w00 : 0.f) + (x1 == bx     ? w01 : 0.f);
        float wB0 = (x0 == bx + 1 ? w00 : 0.f) + (x1 == bx + 1 ? w01 : 0.f);
        float wA1 = (x0 == bx     ? w10 : 0.f) + (x1 == bx     ? w11 : 0.f);
        float wB1 = (x0 == bx + 1 ? w10 : 0.f) + (x1 == bx + 1 ? w11 : 0.f);
        int cy0 = min(max(y0, 0), HH - 1), cy1 = min(max(y1, 0), HH - 1);
        s_off[e][0] = cy0 * WW + bx;
        s_off[e][1] = cy1 * WW + bx;
        s_wq[e][0] = wA0; s_wq[e][1] = wB0; s_wq[e][2] = wA1; s_wq[e][3] = wB1;
    }

    f32x4 acc[2][2];
#pragma unroll
    for (int i = 0; i < 2; ++i)
#pragma unroll
        for (int j = 0; j < 2; ++j) acc[i][j] = (f32x4){0.f, 0.f, 0.f, 0.f};

    const int o_base = wid * 32;
    const int l16 = lane & 15;
    const int lhi = lane >> 4;
    const float* xb = x + (size_t)b * CC * HH * WW;
    const int gpx = t & 31;
    const int gcg = t >> 5;

    for (int c0 = 0; c0 < CC; c0 += 32) {
        for (int kp = 0; kp < KK; ++kp) {
            __syncthreads();
            {
                int o = t & 127;
                int clb = (t >> 7) * 16;
                const float* wpx = weight + (size_t)o * (CC * KK) + (size_t)(c0 + clb) * KK + kp;
                short8 w0, w1;
#pragma unroll
                for (int j = 0; j < 8; ++j) w0[j] = (short)bf16bits(wpx[j * KK]);
#pragma unroll
                for (int j = 0; j < 8; ++j) w1[j] = (short)bf16bits(wpx[(8 + j) * KK]);
                *(short8*)&s_wt6[o][clb] = w0;
                *(short8*)&s_wt6[o][clb + 8] = w1;
            }
            {
                int rec = kp * PXB6 + gpx;
                int o0 = s_off[rec][0], o1 = s_off[rec][1];
                f32x4 wq = *(const f32x4*)&s_wq[rec][0];
                const float* pl = xb + (size_t)(c0 + gcg * 4) * (HH * WW);
                short4v v;
#pragma unroll
                for (int j = 0; j < 4; ++j) {
                    const float* p = pl + (size_t)j * (HH * WW);
                    float2 f0 = *(const float2*)(p + o0);
                    float2 f1 = *(const float2*)(p + o1);
                    float val = wq.x * f0.x + wq.y * f0.y + wq.z * f1.x + wq.w * f1.y;
                    v[j] = (short)bf16bits(val);
                }
                *(short4v*)&s_val6[gpx][gcg * 4] = v;
            }
            __syncthreads();
            short8 afr[2];
#pragma unroll
            for (int mr = 0; mr < 2; ++mr)
                afr[mr] = *(const short8*)&s_wt6[o_base + mr * 16 + l16][lhi * 8];
            short8 bfr[2];
#pragma unroll
            for (int nr = 0; nr < 2; ++nr)
                bfr[nr] = *(const short8*)&s_val6[nr * 16 + l16][lhi * 8];
#pragma unroll
            for (int mr = 0; mr < 2; ++mr)
#pragma unroll
                for (int nr = 0; nr < 2; ++nr)
                    acc[mr][nr] = __builtin_amdgcn_mfma_f32_16x16x32_bf16(
                        afr[mr], bfr[nr], acc[mr][nr], 0, 0, 0);
        }
    }

    float* ob = out + ((size_t)b * COUT) * (HO * WO) + (size_t)ho * WO;
#pragma unroll
    for (int mr = 0; mr < 2; ++mr) {
        int o_r = o_base + mr * 16 + lhi * 4;
#pragma unroll
        for (int r = 0; r < 4; ++r) {
            int o = o_r + r;
            float bs = bias[o];
#pragma unroll
            for (int nr = 0; nr < 2; ++nr) {
                int wo = px0 + nr * 16 + l16;
                ob[(size_t)o * (HO * WO) + wo] = acc[mr][nr][r] + bs;
            }
        }
    }
}

extern "C" void kernel_launch(void* const* d_in, const int* in_sizes, int n_in,
                              void* d_out, int out_size, void* d_ws, size_t ws_size,
                              hipStream_t stream) {
    (void)in_sizes; (void)n_in; (void)out_size;
    const float* x      = (const float*)d_in[0];
    const float* offset = (const float*)d_in[1];
    const float* mask   = (const float*)d_in[2];
    const float* weight = (const float*)d_in[3];
    const float* bias   = (const float*)d_in[4];
    float* out = (float*)d_out;

    const size_t xtoff   = (size_t)1 << 20;                                   // 1 MB
    const size_t xtbytes = (size_t)8 * HH * WW * CC * sizeof(unsigned short); // 32 MB
    const size_t p1off   = xtoff + xtbytes;                                   // 34,603,008
    const size_t p1bytes = (size_t)8 * COUT * HO * WO * sizeof(float);        // 16.8 MB

    if (ws_size >= p1off + p1bytes) {
        unsigned short* wp  = (unsigned short*)d_ws;
        unsigned short* xtp = (unsigned short*)((char*)d_ws + xtoff);
        float* p1           = (float*)((char*)d_ws + p1off);
        prep_kernel<<<dim3(1600), dim3(256), 0, stream>>>(x, xtp, weight, wp);
        dcn18_kernel<true><<<dim3(1024), dim3(256), 0, stream>>>(xtp, offset, mask, wp, bias, out, p1);
        add_kernel<<<dim3(2048), dim3(256), 0, stream>>>(out, p1);
    } else if (ws_size >= xtoff + xtbytes) {
        unsigned short* wp  = (unsigned short*)d_ws;
        unsigned short* xtp = (unsigned short*)((char*)d_ws + xtoff);
        prep_kernel<<<dim3(1600), dim3(256), 0, stream>>>(x, xtp, weight, wp);
        dcn18_kernel<false><<<dim3(512), dim3(256), 0, stream>>>(xtp, offset, mask, wp, bias, out, nullptr);
    } else {
        dcn6_kernel<false><<<dim3(1024), dim3(256), 0, stream>>>(x, offset, mask, weight, nullptr, bias, out);
    }
}

// Round 19
// 59.340 us; speedup vs baseline: 3.9832x; 1.0041x over previous
//
#include <hip/hip_runtime.h>
#include <hip/hip_bf16.h>

typedef __attribute__((ext_vector_type(8))) short short8;
typedef __attribute__((ext_vector_type(4))) short short4v;
typedef __attribute__((ext_vector_type(4))) float f32x4;
typedef __attribute__((ext_vector_type(4))) int int4v;
typedef unsigned long long u64;

#define HH 128
#define WW 128
#define CC 128
#define COUT 128
#define HO 64
#define WO 64
#define KK 9
#define PXB 64
#define NREC (KK * PXB)   /* 576 */

__device__ __forceinline__ unsigned short bf16bits(float f) {
    union { float f; unsigned u; } u; u.f = f;
    unsigned r = u.u + 0x7fffu + ((u.u >> 16) & 1u);
    return (unsigned short)(r >> 16);
}
__device__ __forceinline__ float b2f(unsigned short h) {
    union { unsigned u; float f; } v; v.u = ((unsigned)h) << 16; return v.f;
}

// Fused prep:
//  blocks [0,1024): x NCHW f32 -> xt NHWC bf16 (one block per (b,y));
//  blocks [1024,1600): weight -> wp in MFMA-FRAGMENT-LINEAR layout (R18-exact):
//    wp[ ((kp*2 + chalf)*4 + ot)*2048 + (mr*2+kk)*512 + lane*8 + j ]
//      = bf16( w[o][c][kp] ), o = ot*32 + mr*16 + (lane&15),
//                             c = chalf*64 + kk*32 + (lane>>4)*8 + j.
__global__ __launch_bounds__(256, 4)
void prep_kernel(const float* __restrict__ x, unsigned short* __restrict__ xt,
                 const float* __restrict__ w, unsigned short* __restrict__ wp) {
    const int blk = blockIdx.x;
    const int t = threadIdx.x;
    __shared__ unsigned short tile[128][132];

    if (blk < 1024) {
        const int b = blk >> 7;
        const int y = blk & 127;
        const float* src = x + (((size_t)b * CC) * HH + y) * WW;
#pragma unroll 8
        for (int c0 = 0; c0 < CC; c0 += 2) {
            int c = c0 + (t >> 7);
            int xx = t & 127;
            tile[xx][c] = bf16bits(src[(size_t)c * (HH * WW) + xx]);
        }
        __syncthreads();
        unsigned short* dst = xt + (((size_t)b * HH + y) * WW) * CC;
#pragma unroll
        for (int it = 0; it < 4; ++it) {
            int lin = it * 256 + t;
            int xx = lin >> 3;
            int cb = (lin & 7) * 16;
            const u64* lp = (const u64*)&tile[xx][cb];
            u64* op = (u64*)(dst + (size_t)xx * CC + cb);
            op[0] = lp[0]; op[1] = lp[1]; op[2] = lp[2]; op[3] = lp[3];
        }
    } else {
        int i = (blk - 1024) * 256 + t;          // 0 .. 147455 exactly
        int tileid = i >> 11;                    // kp*8 + chalf*4 + ot
        int inner = i & 2047;
        int kp = tileid >> 3;
        int chalf = (tileid >> 2) & 1;
        int ot = tileid & 3;
        int mrkk = inner >> 9;                   // mr*2 + kk
        int l = (inner >> 3) & 63;
        int j = inner & 7;
        int o = ot * 32 + (mrkk >> 1) * 16 + (l & 15);
        int c = chalf * 64 + (mrkk & 1) * 32 + (l >> 4) * 8 + j;
        wp[i] = bf16bits(w[((size_t)o * CC + c) * KK + kp]);
    }
}

// out += part1   (R14-verbatim)
__global__ __launch_bounds__(256, 8)
void add_kernel(float* __restrict__ out, const float* __restrict__ p1) {
    size_t i = ((size_t)blockIdx.x * 256 + threadIdx.x) * 4;
    const size_t N = (size_t)8 * COUT * HO * WO;
    const size_t STR = (size_t)2048 * 256 * 4;
    for (; i < N; i += STR) {
        f32x4 a = *(const f32x4*)(out + i);
        f32x4 b = *(const f32x4*)(p1 + i);
        a = a + b;
        *(f32x4*)(out + i) = a;
    }
}

// Main kernel: R18 VERBATIM except the gather lane map: 8 CONTIGUOUS lanes
// now cover one px's full 128B channel-segment in ONE wave-instr (each thread
// handles px pp and pp+32, 8 ch each, 4 corners). Same 8x16B loads/thread,
// identical s_val contents — pure address permutation (R8->R9-proven class).
template <bool SPLIT>
__global__ __launch_bounds__(256, 4)
void dcn19_kernel(const unsigned short* __restrict__ xt, const float* __restrict__ offset,
                  const float* __restrict__ mask, const unsigned short* __restrict__ wprep,
                  const float* __restrict__ bias, float* __restrict__ out,
                  float* __restrict__ part1) {
    const int blk = blockIdx.x;
    const int b = blk & 7;               // XCD i streams batch image i
    const int ho = (blk >> 3) & 63;
    const int chalf = SPLIT ? (blk >> 9) : 0;
    const int t = threadIdx.x;
    const int lane = t & 63;
    const int wid = t >> 6;

    __shared__ int            s_cidx[NREC][4];   // corner offsets, pre-scaled by CC
    __shared__ float          s_w[NREC][4];      // bilinear weights * mask (0 if OOB)
    __shared__ unsigned short s_val[PXB][72];    // bf16 val tile [px 64][c64 pad72]

    // ---- per-(kp,wo) sampling records (same math as R1/R5/R7/R9/R14) ----
    for (int e = t; e < NREC; e += 256) {
        int kp = e >> 6;
        int wo = e & 63;
        int ky = kp / 3, kx = kp - ky * 3;
        float dy = offset[(((size_t)b * 18 + 2 * kp    ) * HO + ho) * WO + wo];
        float dx = offset[(((size_t)b * 18 + 2 * kp + 1) * HO + ho) * WO + wo];
        float m  = mask  [(((size_t)b * 9  + kp        ) * HO + ho) * WO + wo];
        float py = dy + (float)(2 * ho - 1 + ky);
        float px = dx + (float)(2 * wo - 1 + kx);
        float fy0 = floorf(py), fx0 = floorf(px);
        float ay = py - fy0, ax = px - fx0;
        int y0 = (int)fy0, x0 = (int)fx0;
        int y1 = y0 + 1, x1 = x0 + 1;
        bool vy0 = (unsigned)y0 < HH, vy1 = (unsigned)y1 < HH;
        bool vx0 = (unsigned)x0 < WW, vx1 = (unsigned)x1 < WW;
        float w00 = (vy0 && vx0) ? (1.f - ay) * (1.f - ax) * m : 0.f;
        float w01 = (vy0 && vx1) ? (1.f - ay) * ax * m : 0.f;
        float w10 = (vy1 && vx0) ? ay * (1.f - ax) * m : 0.f;
        float w11 = (vy1 && vx1) ? ay * ax * m : 0.f;
        int cy0 = min(max(y0, 0), HH - 1), cy1 = min(max(y1, 0), HH - 1);
        int cx0 = min(max(x0, 0), WW - 1), cx1 = min(max(x1, 0), WW - 1);
        s_cidx[e][0] = (cy0 * WW + cx0) * CC;
        s_cidx[e][1] = (cy0 * WW + cx1) * CC;
        s_cidx[e][2] = (cy1 * WW + cx0) * CC;
        s_cidx[e][3] = (cy1 * WW + cx1) * CC;
        s_w[e][0] = w00; s_w[e][1] = w01; s_w[e][2] = w10; s_w[e][3] = w11;
    }

    f32x4 acc[2][4];
#pragma unroll
    for (int i = 0; i < 2; ++i)
#pragma unroll
        for (int j = 0; j < 4; ++j) acc[i][j] = (f32x4){0.f, 0.f, 0.f, 0.f};

    const int o_base = wid * 32;         // 4 waves x 32 o
    const int l16 = lane & 15;
    const int lhi = lane >> 4;

    const unsigned short* xtb = xt + (size_t)b * (HH * WW * CC);
    const int pp  = t >> 3;              // px group base (0..31); also handles pp+32
    const int gcb = (t & 7) * 8;         // channel base (8 ch = 16B); 8 lanes cover 128B

    const int cbeg = SPLIT ? chalf * 64 : 0;
    const int cend = SPLIT ? cbeg + 64 : CC;

    for (int c0 = cbeg; c0 < cend; c0 += 64) {
        for (int kp = 0; kp < KK; ++kp) {
            __syncthreads();             // (A) previous window's LDS reads complete

            // ---- dense gather: 2 px x 4 corners x 8 ch (8x16B, fully coalesced) ----
            int rec0 = kp * PXB + pp;
            int rec1 = rec0 + 32;
            int4v ci0 = *(const int4v*)&s_cidx[rec0][0];
            f32x4 wq0 = *(const f32x4*)&s_w[rec0][0];
            int4v ci1 = *(const int4v*)&s_cidx[rec1][0];
            f32x4 wq1 = *(const f32x4*)&s_w[rec1][0];
            const unsigned short* bp = xtb + c0 + gcb;
            short8 a00 = *(const short8*)(bp + ci0.x);
            short8 a01 = *(const short8*)(bp + ci0.y);
            short8 a10 = *(const short8*)(bp + ci0.z);
            short8 a11 = *(const short8*)(bp + ci0.w);
            short8 c00 = *(const short8*)(bp + ci1.x);
            short8 c01 = *(const short8*)(bp + ci1.y);
            short8 c10 = *(const short8*)(bp + ci1.z);
            short8 c11 = *(const short8*)(bp + ci1.w);

            // ---- weight fragments: fragment-linear wp, lane-contiguous 16B (R18) ----
            const unsigned short* wb =
                wprep + ((size_t)((kp * 2 + (c0 >> 6)) * 4 + wid) << 11) + lane * 8;
            short8 afr[2][2];
#pragma unroll
            for (int mr = 0; mr < 2; ++mr)
#pragma unroll
                for (int kk = 0; kk < 2; ++kk)
                    afr[mr][kk] = *(const short8*)(wb + ((mr * 2 + kk) << 9));

            short8 v0, v1;
#pragma unroll
            for (int j = 0; j < 8; ++j) {
                float val = wq0.x * b2f((unsigned short)a00[j]) + wq0.y * b2f((unsigned short)a01[j])
                          + wq0.z * b2f((unsigned short)a10[j]) + wq0.w * b2f((unsigned short)a11[j]);
                v0[j] = (short)bf16bits(val);
            }
#pragma unroll
            for (int j = 0; j < 8; ++j) {
                float val = wq1.x * b2f((unsigned short)c00[j]) + wq1.y * b2f((unsigned short)c01[j])
                          + wq1.z * b2f((unsigned short)c10[j]) + wq1.w * b2f((unsigned short)c11[j]);
                v1[j] = (short)bf16bits(val);
            }
            *(short8*)&s_val[pp][gcb] = v0;
            *(short8*)&s_val[pp + 32][gcb] = v1;

            __syncthreads();             // (B) val tile visible

#pragma unroll
            for (int nr = 0; nr < 4; ++nr) {
                short8 bfr[2];
#pragma unroll
                for (int kk = 0; kk < 2; ++kk)
                    bfr[kk] = *(const short8*)&s_val[nr * 16 + l16][kk * 32 + lhi * 8];
#pragma unroll
                for (int mr = 0; mr < 2; ++mr)
#pragma unroll
                    for (int kk = 0; kk < 2; ++kk)
                        acc[mr][nr] = __builtin_amdgcn_mfma_f32_16x16x32_bf16(
                            afr[mr][kk], bfr[kk], acc[mr][nr], 0, 0, 0);
            }
        }
    }

    // ---- epilogue (R14-verbatim) ----
    float* dst = (SPLIT && chalf == 1) ? part1 : out;
    const bool addb = (!SPLIT) || (chalf == 0);
    float* ob = dst + ((size_t)b * COUT) * (HO * WO) + (size_t)ho * WO;
#pragma unroll
    for (int mr = 0; mr < 2; ++mr) {
        int o_r = o_base + mr * 16 + lhi * 4;
#pragma unroll
        for (int r = 0; r < 4; ++r) {
            int o = o_r + r;
            float bs = addb ? bias[o] : 0.f;
#pragma unroll
            for (int nr = 0; nr < 4; ++nr) {
                int wo = nr * 16 + l16;
                ob[(size_t)o * (HO * WO) + wo] = acc[mr][nr][r] + bs;
            }
        }
    }
}

// ---------------- R6 fallback (verbatim), used only if d_ws is too small ----------------
#define PXB6 32
#define NREC6 (KK * PXB6)
template <bool PREP>
__global__ __launch_bounds__(256, 4)
void dcn6_kernel(const float* __restrict__ x, const float* __restrict__ offset,
                 const float* __restrict__ mask, const float* __restrict__ weight,
                 const unsigned short* __restrict__ wprep,
                 const float* __restrict__ bias, float* __restrict__ out) {
    const int blk = blockIdx.x;
    const int b = blk & 7;
    const int rr = blk >> 3;
    const int ho = rr >> 1;
    const int px0 = (rr & 1) * PXB6;
    const int t = threadIdx.x;
    const int lane = t & 63;
    const int wid = t >> 6;

    __shared__ int            s_off[NREC6][2];
    __shared__ float          s_wq[NREC6][4];
    __shared__ unsigned short s_wt6[COUT][40];
    __shared__ unsigned short s_val6[PXB6][40];

    for (int e = t; e < NREC6; e += 256) {
        int kp = e >> 5;
        int wo = px0 + (e & 31);
        int ky = kp / 3, kx = kp - ky * 3;
        float dy = offset[(((size_t)b * 18 + 2 * kp    ) * HO + ho) * WO + wo];
        float dx = offset[(((size_t)b * 18 + 2 * kp + 1) * HO + ho) * WO + wo];
        float m  = mask  [(((size_t)b * 9  + kp        ) * HO + ho) * WO + wo];
        float py = dy + (float)(2 * ho - 1 + ky);
        float px = dx + (float)(2 * wo - 1 + kx);
        float fy0 = floorf(py), fx0 = floorf(px);
        float ay = py - fy0, ax = px - fx0;
        int y0 = (int)fy0, x0 = (int)fx0;
        int y1 = y0 + 1, x1 = x0 + 1;
        bool vy0 = (unsigned)y0 < HH, vy1 = (unsigned)y1 < HH;
        bool vx0 = (unsigned)x0 < WW, vx1 = (unsigned)x1 < WW;
        float w00 = (vy0 && vx0) ? (1.f - ay) * (1.f - ax) * m : 0.f;
        float w01 = (vy0 && vx1) ? (1.f - ay) * ax * m : 0.f;
        float w10 = (vy1 && vx0) ? ay * (1.f - ax) * m : 0.f;
        float w11 = (vy1 && vx1) ? ay * ax * m : 0.f;
        int bx = min(max(x0, 0), WW - 2);
        float wA0 = (x0 == bx     ? w00 : 0.f) + (x1 == bx     ? w01 : 0.f);
        float wB0 = (x0 == bx + 1 ? w00 : 0.f) + (x1 == bx + 1 ? w01 : 0.f);
        float wA1 = (x0 == bx     ? w10 : 0.f) + (x1 == bx     ? w11 : 0.f);
        float wB1 = (x0 == bx + 1 ? w10 : 0.f) + (x1 == bx + 1 ? w11 : 0.f);
        int cy0 = min(max(y0, 0), HH - 1), cy1 = min(max(y1, 0), HH - 1);
        s_off[e][0] = cy0 * WW + bx;
        s_off[e][1] = cy1 * WW + bx;
        s_wq[e][0] = wA0; s_wq[e][1] = wB0; s_wq[e][2] = wA1; s_wq[e][3] = wB1;
    }

    f32x4 acc[2][2];
#pragma unroll
    for (int i = 0; i < 2; ++i)
#pragma unroll
        for (int j = 0; j < 2; ++j) acc[i][j] = (f32x4){0.f, 0.f, 0.f, 0.f};

    const int o_base = wid * 32;
    const int l16 = lane & 15;
    const int lhi = lane >> 4;
    const float* xb = x + (size_t)b * CC * HH * WW;
    const int gpx = t & 31;
    const int gcg = t >> 5;

    for (int c0 = 0; c0 < CC; c0 += 32) {
        for (int kp = 0; kp < KK; ++kp) {
            __syncthreads();
            {
                int o = t & 127;
                int clb = (t >> 7) * 16;
                const float* wpx = weight + (size_t)o * (CC * KK) + (size_t)(c0 + clb) * KK + kp;
                short8 w0, w1;
#pragma unroll
                for (int j = 0; j < 8; ++j) w0[j] = (short)bf16bits(wpx[j * KK]);
#pragma unroll
                for (int j = 0; j < 8; ++j) w1[j] = (short)bf16bits(wpx[(8 + j) * KK]);
                *(short8*)&s_wt6[o][clb] = w0;
                *(short8*)&s_wt6[o][clb + 8] = w1;
            }
            {
                int rec = kp * PXB6 + gpx;
                int o0 = s_off[rec][0], o1 = s_off[rec][1];
                f32x4 wq = *(const f32x4*)&s_wq[rec][0];
                const float* pl = xb + (size_t)(c0 + gcg * 4) * (HH * WW);
                short4v v;
#pragma unroll
                for (int j = 0; j < 4; ++j) {
                    const float* p = pl + (size_t)j * (HH * WW);
                    float2 f0 = *(const float2*)(p + o0);
                    float2 f1 = *(const float2*)(p + o1);
                    float val = wq.x * f0.x + wq.y * f0.y + wq.z * f1.x + wq.w * f1.y;
                    v[j] = (short)bf16bits(val);
                }
                *(short4v*)&s_val6[gpx][gcg * 4] = v;
            }
            __syncthreads();
            short8 afr[2];
#pragma unroll
            for (int mr = 0; mr < 2; ++mr)
                afr[mr] = *(const short8*)&s_wt6[o_base + mr * 16 + l16][lhi * 8];
            short8 bfr[2];
#pragma unroll
            for (int nr = 0; nr < 2; ++nr)
                bfr[nr] = *(const short8*)&s_val6[nr * 16 + l16][lhi * 8];
#pragma unroll
            for (int mr = 0; mr < 2; ++mr)
#pragma unroll
                for (int nr = 0; nr < 2; ++nr)
                    acc[mr][nr] = __builtin_amdgcn_mfma_f32_16x16x32_bf16(
                        afr[mr], bfr[nr], acc[mr][nr], 0, 0, 0);
        }
    }

    float* ob = out + ((size_t)b * COUT) * (HO * WO) + (size_t)ho * WO;
#pragma unroll
    for (int mr = 0; mr < 2; ++mr) {
        int o_r = o_base + mr * 16 + lhi * 4;
#pragma unroll
        for (int r = 0; r < 4; ++r) {
            int o = o_r + r;
            float bs = bias[o];
#pragma unroll
            for (int nr = 0; nr < 2; ++nr) {
                int wo = px0 + nr * 16 + l16;
                ob[(size_t)o * (HO * WO) + wo] = acc[mr][nr][r] + bs;
            }
        }
    }
}

extern "C" void kernel_launch(void* const* d_in, const int* in_sizes, int n_in,
                              void* d_out, int out_size, void* d_ws, size_t ws_size,
                              hipStream_t stream) {
    (void)in_sizes; (void)n_in; (void)out_size;
    const float* x      = (const float*)d_in[0];
    const float* offset = (const float*)d_in[1];
    const float* mask   = (const float*)d_in[2];
    const float* weight = (const float*)d_in[3];
    const float* bias   = (const float*)d_in[4];
    float* out = (float*)d_out;

    const size_t xtoff   = (size_t)1 << 20;                                   // 1 MB
    const size_t xtbytes = (size_t)8 * HH * WW * CC * sizeof(unsigned short); // 32 MB
    const size_t p1off   = xtoff + xtbytes;                                   // 34,603,008
    const size_t p1bytes = (size_t)8 * COUT * HO * WO * sizeof(float);        // 16.8 MB

    if (ws_size >= p1off + p1bytes) {
        unsigned short* wp  = (unsigned short*)d_ws;
        unsigned short* xtp = (unsigned short*)((char*)d_ws + xtoff);
        float* p1           = (float*)((char*)d_ws + p1off);
        prep_kernel<<<dim3(1600), dim3(256), 0, stream>>>(x, xtp, weight, wp);
        dcn19_kernel<true><<<dim3(1024), dim3(256), 0, stream>>>(xtp, offset, mask, wp, bias, out, p1);
        add_kernel<<<dim3(2048), dim3(256), 0, stream>>>(out, p1);
    } else if (ws_size >= xtoff + xtbytes) {
        unsigned short* wp  = (unsigned short*)d_ws;
        unsigned short* xtp = (unsigned short*)((char*)d_ws + xtoff);
        prep_kernel<<<dim3(1600), dim3(256), 0, stream>>>(x, xtp, weight, wp);
        dcn19_kernel<false><<<dim3(512), dim3(256), 0, stream>>>(xtp, offset, mask, wp, bias, out, nullptr);
    } else {
        dcn6_kernel<false><<<dim3(1024), dim3(256), 0, stream>>>(x, offset, mask, weight, nullptr, bias, out);
    }
}